// Round 1
// baseline (231.714 us; speedup 1.0000x reference)
//
#include <hip/hip_runtime.h>
#include <stdint.h>

// Problem constants (reference: B=4, S=2048, D=512, H=8, d_head=64)
#define NB  4
#define SS  2048
#define DD  512
#define HH  8
#define DHH 64
#define MM  (NB * SS)   // 8192 rows

typedef __attribute__((ext_vector_type(8))) short bf16x8;  // 8 bf16 in 4 VGPRs
typedef __attribute__((ext_vector_type(4))) float f32x4;   // MFMA C/D frag
typedef __attribute__((ext_vector_type(4))) short s16x4;   // 8 B pack

union fu32 { float f; unsigned u; };
union pfu  { uint4 u; bf16x8 v; };

// fp32 -> bf16 round-to-nearest-even (bit pattern in a short)
static __device__ __forceinline__ short f2bf(float f) {
  fu32 a; a.f = f;
  unsigned u = a.u;
  return (short)((u + 0x7fffu + ((u >> 16) & 1u)) >> 16);
}
static __device__ __forceinline__ float bf2f(short s) {
  fu32 t; t.u = ((unsigned)(unsigned short)s) << 16;
  return t.f;
}

// async global->LDS, 16 B/lane; LDS dest = wave-uniform base + lane*16
static __device__ __forceinline__ void async16(const void* g, void* l) {
  __builtin_amdgcn_global_load_lds(
      (__attribute__((address_space(1))) unsigned*)(void*)g,
      (__attribute__((address_space(3))) unsigned*)l, 16, 0, 0);
}

// ------------------------------- prep: x->bf16 (blocks 0..2047) and
//                                 W[k][n] fp32 -> Wt[n][k] bf16 (2048..2303)
__global__ __launch_bounds__(256) void prep_kernel(
    const float* __restrict__ x, short* __restrict__ xb,
    const float* __restrict__ W0, const float* __restrict__ W1,
    const float* __restrict__ W2, const float* __restrict__ W3,
    short* __restrict__ T0, short* __restrict__ T1,
    short* __restrict__ T2, short* __restrict__ T3) {
  const int bid = blockIdx.x, tid = threadIdx.x;
  if (bid < 2048) {
    int i = (bid * 256 + tid) * 8;
    float4 v0 = *(const float4*)(x + i);
    float4 v1 = *(const float4*)(x + i + 4);
    bf16x8 o;
    o[0] = f2bf(v0.x); o[1] = f2bf(v0.y); o[2] = f2bf(v0.z); o[3] = f2bf(v0.w);
    o[4] = f2bf(v1.x); o[5] = f2bf(v1.y); o[6] = f2bf(v1.z); o[7] = f2bf(v1.w);
    *(bf16x8*)(xb + i) = o;
  } else {
    int z = bid - 2048;                 // 0..255
    int widx = z >> 6, rem = z & 63;
    const float* W = widx == 0 ? W0 : widx == 1 ? W1 : widx == 2 ? W2 : W3;
    short*       T = widx == 0 ? T0 : widx == 1 ? T1 : widx == 2 ? T2 : T3;
    int n  = (rem & 7) * 64 + (tid & 63);
    int k0 = (rem >> 3) * 64 + (tid >> 6) * 16;
    bf16x8 t0, t1;
#pragma unroll
    for (int j = 0; j < 8; ++j) t0[j] = f2bf(W[(size_t)(k0 + j) * DD + n]);
#pragma unroll
    for (int j = 0; j < 8; ++j) t1[j] = f2bf(W[(size_t)(k0 + 8 + j) * DD + n]);
    *(bf16x8*)(T + (size_t)n * DD + k0)     = t0;
    *(bf16x8*)(T + (size_t)n * DD + k0 + 8) = t1;
  }
}

// ---------------------------------------- fused QKV GEMM: 128x128, N = 1536
// m97-structure: grid (12,64) = 768 blocks -> 3 blocks/CU exact, 4x4 acc per
// wave (0.5 ds_read:MFMA ratio), BK=64, global_load_lds staging with
// XOR-swizzled segments.
// Epilogue: q,k -> [B,H,S,64] bf16 (q pre-scaled), v -> [B,H,64,S] bf16.
__global__ __launch_bounds__(256, 3) void gemm_qkv_kernel(
    const short* __restrict__ A, const short* __restrict__ Bt,
    const float* __restrict__ bq, const float* __restrict__ bk,
    const float* __restrict__ bv, short* __restrict__ qout,
    short* __restrict__ kout, short* __restrict__ vtout, float qscale) {
  __shared__ __align__(16) short a_sh[128 * 64];
  __shared__ __align__(16) short b_sh[128 * 64];
  const int tid  = threadIdx.x;
  const int w    = tid >> 6, lane = tid & 63, quad = lane >> 4, l16 = lane & 15;
  const int m0   = blockIdx.y * 128, n0 = blockIdx.x * 128;
  const int mw   = (w >> 1) * 64,    nw = (w & 1) * 64;
  const int rw   = lane >> 3, seg = lane & 7, gs = seg ^ rw;  // row&7 == rw
  const int sxz  = l16 & 7;   // fragment-read swizzle key

  f32x4 acc[4][4];
#pragma unroll
  for (int i = 0; i < 4; ++i)
#pragma unroll
    for (int j = 0; j < 4; ++j) acc[i][j] = {0.f, 0.f, 0.f, 0.f};

  for (int kt = 0; kt < DD; kt += 64) {
    __syncthreads();
    {
      const short* ga = A  + (size_t)(m0 + w * 32 + rw) * DD + kt + gs * 8;
      const short* gb = Bt + (size_t)(n0 + w * 32 + rw) * DD + kt + gs * 8;
#pragma unroll
      for (int i = 0; i < 4; ++i)
        async16(ga + (size_t)i * 8 * DD, &a_sh[(w * 32 + i * 8) * 64]);
#pragma unroll
      for (int i = 0; i < 4; ++i)
        async16(gb + (size_t)i * 8 * DD, &b_sh[(w * 32 + i * 8) * 64]);
    }
    __syncthreads();
#pragma unroll
    for (int ks = 0; ks < 2; ++ks) {
      const int so = ((ks * 4 + quad) ^ sxz) * 8;
      bf16x8 af[4], bfr[4];
#pragma unroll
      for (int mt = 0; mt < 4; ++mt)
        af[mt] = *(const bf16x8*)&a_sh[(mw + mt * 16 + l16) * 64 + so];
#pragma unroll
      for (int nt = 0; nt < 4; ++nt)
        bfr[nt] = *(const bf16x8*)&b_sh[(nw + nt * 16 + l16) * 64 + so];
#pragma unroll
      for (int mt = 0; mt < 4; ++mt)
#pragma unroll
        for (int nt = 0; nt < 4; ++nt)
          acc[mt][nt] = __builtin_amdgcn_mfma_f32_16x16x32_bf16(
              af[mt], bfr[nt], acc[mt][nt], 0, 0, 0);
    }
  }

#pragma unroll
  for (int nt = 0; nt < 4; ++nt) {
    const int n   = n0 + nw + nt * 16 + l16;   // 0..1535
    const int sg  = n >> 9, n9 = n & 511, h = n9 >> 6, d = n & 63;
    const float bval = (sg == 0 ? bq : sg == 1 ? bk : bv)[n9];
    const float scl  = (sg == 0) ? qscale : 1.0f;
#pragma unroll
    for (int mt = 0; mt < 4; ++mt) {
      const int mb = m0 + mw + mt * 16 + quad * 4;   // C row = quad*4 + r
      const int bi = mb >> 11, s = mb & (SS - 1);
      if (sg == 2) {
        s16x4 pk;
#pragma unroll
        for (int r = 0; r < 4; ++r) pk[r] = f2bf(acc[mt][nt][r] + bval);
        *(s16x4*)&vtout[((size_t)(bi * HH + h) * DHH + d) * SS + s] = pk;
      } else {
        short* o = (sg == 0) ? qout : kout;
        const size_t base = ((size_t)(bi * HH + h) * SS + s) * DHH + d;
#pragma unroll
        for (int r = 0; r < 4; ++r)
          o[base + (size_t)r * DHH] = f2bf((acc[mt][nt][r] + bval) * scl);
      }
    }
  }
}

// ----------------------------------------------- flash attention, key-split
// S^T = K·Q^T; P fragments assembled in registers (pack -> ^16 exchange ->
// select -> 4 ds_bpermute); softmax denominator via MFMA-vs-ones (C-layout
// matches O -> zero-shuffle normalization).  Raw v_exp_f32 via
// __builtin_amdgcn_exp2f (scores bounded, no range fixup needed).
// T14 async-STAGE split: next K/V tile is loaded into VGPRs right after the
// compute barrier (HBM latency hides under MFMA/exp2 of the current tile);
// ds_write_b128 lands after the WAR barrier.  Reg-stage reproduces the
// global_load_lds layout exactly (per-lane global addr, lane*16 LDS dest).
__global__ __launch_bounds__(256, 4) void attn_kernel(
    const short* __restrict__ Qa, const short* __restrict__ Ka,
    const short* __restrict__ Vt, short* __restrict__ Op0,
    short* __restrict__ Op1, float* __restrict__ lpw) {
  __shared__ __align__(16) short k_sh[128 * 64];     // K tile, swizzled segs
  __shared__ __align__(16) short vt_sh[64 * 128];    // V^T tile, swizzled segs

  const int tid  = threadIdx.x;
  const int w    = tid >> 6, lane = tid & 63, quad = lane >> 4, l16 = lane & 15;
  // XCD-aware decode: xcd = n&7 (dispatch heuristic), 8 groups x 16 qt per XCD
  const int n    = blockIdx.x;
  const int grp  = (n & 7) * 8 + (n >> 7);   // (b,h,half) group, 0..63
  const int qt_b = (n >> 3) & 15;
  const int half = grp & 1, h = (grp >> 1) & 7, b = grp >> 4;
  const int q0   = qt_b * 128;
  const int rw = lane >> 3, seg = lane & 7, gs = seg ^ rw;
  const int sxz = l16 & 7;
  const size_t base = (size_t)(b * HH + h) * SS * DHH;
  const short* Qg = Qa + base + (size_t)(q0 + w * 32) * DHH;
  const short* Kg = Ka + base;
  const short* Vg = Vt + base;           // [64][S]

  // Q fragments (usable as A or B operand: same lane map)
  bf16x8 qf[2][2];
#pragma unroll
  for (int mt = 0; mt < 2; ++mt)
#pragma unroll
    for (int ks = 0; ks < 2; ++ks)
      qf[mt][ks] = *(const bf16x8*)(Qg + (size_t)(mt * 16 + l16) * DHH + ks * 32 + quad * 8);

  bf16x8 ones;
#pragma unroll
  for (int j = 0; j < 8; ++j) ones[j] = (short)0x3F80;   // bf16 1.0

  f32x4 o_acc[2][4];
#pragma unroll
  for (int qt = 0; qt < 2; ++qt)
#pragma unroll
    for (int dt = 0; dt < 4; ++dt) o_acc[qt][dt] = {0.f, 0.f, 0.f, 0.f};
  f32x4 l_acc[2] = {{0.f, 0.f, 0.f, 0.f}, {0.f, 0.f, 0.f, 0.f}};

  // bpermute byte-addresses for the verified cross-quad gather:
  // dwords 0/1 pull from src_quad = (quad&1)*2 + (quad>>1); dwords 2/3 from ^1
  const int addrA = ((((quad & 1) << 1) + (quad >> 1)) * 16 + l16) * 4;
  const int addrB = addrA ^ 64;
  const bool qeven = (quad & 1) == 0;

  const int kstart = half * (SS / 2);
  const int kend   = kstart + SS / 2;

  // V-load per-lane geometry (kb-invariant)
  const int vd0   = w * 16 + (lane >> 4);          // + i*4
  // prologue: stage first K/V tile into registers
  uint4 kr[4], vr[4];
#pragma unroll
  for (int i = 0; i < 4; ++i)
    kr[i] = *(const uint4*)(Kg + (size_t)(kstart + w * 32 + i * 8 + rw) * DHH + gs * 8);
#pragma unroll
  for (int i = 0; i < 4; ++i) {
    const int d = vd0 + i * 4;
    const int gseg = l16 ^ (d & 15);
    vr[i] = *(const uint4*)(Vg + (size_t)d * SS + kstart + gseg * 8);
  }

  for (int kb = kstart; kb < kend; kb += 128) {
    __syncthreads();   // WAR on k_sh / vt_sh
    // write staged tile (reg -> LDS, same layout as global_load_lds)
#pragma unroll
    for (int i = 0; i < 4; ++i)
      *(uint4*)((char*)&k_sh[(w * 32 + i * 8) * 64] + lane * 16) = kr[i];
#pragma unroll
    for (int i = 0; i < 4; ++i)
      *(uint4*)((char*)&vt_sh[(w * 16 + i * 4) * 128] + lane * 16) = vr[i];
    __syncthreads();

    // issue next tile's global loads now; latency hides under compute
    if (kb + 128 < kend) {
      const int nkb = kb + 128;
#pragma unroll
      for (int i = 0; i < 4; ++i)
        kr[i] = *(const uint4*)(Kg + (size_t)(nkb + w * 32 + i * 8 + rw) * DHH + gs * 8);
#pragma unroll
      for (int i = 0; i < 4; ++i) {
        const int d = vd0 + i * 4;
        const int gseg = l16 ^ (d & 15);
        vr[i] = *(const uint4*)(Vg + (size_t)d * SS + nkb + gseg * 8);
      }
    }

    // 4 chunks of 32 keys: QK^T (2 tiles) -> exp2/pack -> permute -> PV + l
#pragma unroll
    for (int ck = 0; ck < 4; ++ck) {
      uint2 pk[2][2];   // [qt][tile]
#pragma unroll
      for (int t = 0; t < 2; ++t) {
        const int knt = ck * 2 + t;
        bf16x8 kf0 = *(const bf16x8*)&k_sh[(knt * 16 + l16) * 64 + ((0 * 4 + quad) ^ sxz) * 8];
        bf16x8 kf1 = *(const bf16x8*)&k_sh[(knt * 16 + l16) * 64 + ((1 * 4 + quad) ^ sxz) * 8];
#pragma unroll
        for (int qt = 0; qt < 2; ++qt) {
          f32x4 s = {0.f, 0.f, 0.f, 0.f};
          s = __builtin_amdgcn_mfma_f32_16x16x32_bf16(kf0, qf[qt][0], s, 0, 0, 0);
          s = __builtin_amdgcn_mfma_f32_16x16x32_bf16(kf1, qf[qt][1], s, 0, 0, 0);
          fu32 e0, e1, e2, e3;
          e0.f = __builtin_amdgcn_exp2f(s[0]);
          e1.f = __builtin_amdgcn_exp2f(s[1]);
          e2.f = __builtin_amdgcn_exp2f(s[2]);
          e3.f = __builtin_amdgcn_exp2f(s[3]);
          pk[qt][t].x = __builtin_amdgcn_perm(e1.u, e0.u, 0x07060302u);
          pk[qt][t].y = __builtin_amdgcn_perm(e3.u, e2.u, 0x07060302u);
        }
      }
      // assemble A-layout P fragments (32 keys) in registers
      pfu pf[2];
#pragma unroll
      for (int qt = 0; qt < 2; ++qt) {
        // pre-exchange pk[1] across quad^1 (lane^16)
        unsigned p1x = (unsigned)__shfl_xor((int)pk[qt][1].x, 16);
        unsigned p1y = (unsigned)__shfl_xor((int)pk[qt][1].y, 16);
        // per-dword contributions (source-lane side)
        unsigned v0x = qeven ? pk[qt][0].x : p1x;
        unsigned v0y = qeven ? pk[qt][0].y : p1y;
        unsigned v2x = qeven ? p1x : pk[qt][0].x;
        unsigned v2y = qeven ? p1y : pk[qt][0].y;
        pf[qt].u.x = (unsigned)__builtin_amdgcn_ds_bpermute(addrA, (int)v0x);
        pf[qt].u.y = (unsigned)__builtin_amdgcn_ds_bpermute(addrA, (int)v0y);
        pf[qt].u.z = (unsigned)__builtin_amdgcn_ds_bpermute(addrB, (int)v2x);
        pf[qt].u.w = (unsigned)__builtin_amdgcn_ds_bpermute(addrB, (int)v2y);
        l_acc[qt] = __builtin_amdgcn_mfma_f32_16x16x32_bf16(pf[qt].v, ones, l_acc[qt], 0, 0, 0);
      }
#pragma unroll
      for (int dt = 0; dt < 4; ++dt) {
        bf16x8 vf = *(const bf16x8*)&vt_sh[(dt * 16 + l16) * 128 + ((ck * 4 + quad) ^ l16) * 8];
        o_acc[0][dt] = __builtin_amdgcn_mfma_f32_16x16x32_bf16(pf[0].v, vf, o_acc[0][dt], 0, 0, 0);
        o_acc[1][dt] = __builtin_amdgcn_mfma_f32_16x16x32_bf16(pf[1].v, vf, o_acc[1][dt], 0, 0, 0);
      }
    }
  }

  // epilogue: l_acc is in the same C-layout as o_acc (row = query quad*4+r,
  // value replicated across l16) -> zero-shuffle normalization.
  short* Op = half ? Op1 : Op0;
#pragma unroll
  for (int qt = 0; qt < 2; ++qt) {
#pragma unroll
    for (int r = 0; r < 4; ++r) {
      const int qg = q0 + w * 32 + qt * 16 + quad * 4 + r;
      const size_t row = (size_t)(b * HH + h) * SS + qg;
      if (l16 == 0)
        lpw[(size_t)half * (NB * HH * SS) + row] = l_acc[qt][r];
      const float inv = __builtin_amdgcn_rcpf(l_acc[qt][r]);
#pragma unroll
      for (int dt = 0; dt < 4; ++dt)
        Op[row * DHH + dt * 16 + l16] = f2bf(o_acc[qt][dt][r] * inv);
    }
  }
}

// ------------------------------------- merge the two key-halves -> aws bf16
__global__ void attn_combine_kernel(const short* __restrict__ Op0,
                                    const short* __restrict__ Op1,
                                    const float* __restrict__ lpw,
                                    short* __restrict__ aws) {
  int idx  = blockIdx.x * 256 + threadIdx.x;   // over B*H*S*8 segments
  int dsg  = idx & 7;
  int row  = idx >> 3;                         // (b*H + h)*S + q
  int q    = row & (SS - 1);
  int bh   = row >> 11, h = bh & 7, b = bh >> 3;
  float l1 = lpw[row], l2 = lpw[NB * HH * SS + row];
  float inv = 1.f / (l1 + l2);
  float w1 = l1 * inv, w2 = l2 * inv;
  bf16x8 a = *(const bf16x8*)&Op0[(size_t)row * DHH + dsg * 8];
  bf16x8 c = *(const bf16x8*)&Op1[(size_t)row * DHH + dsg * 8];
  bf16x8 o;
#pragma unroll
  for (int j = 0; j < 8; ++j) o[j] = f2bf(w1 * bf2f(a[j]) + w2 * bf2f(c[j]));
  *(bf16x8*)&aws[((size_t)(b * SS + q)) * DD + h * DHH + dsg * 8] = o;
}

// ------------------------------------------- output projection: 64x64 tile
// grid (8,128) = 1024 blocks -> 4 blocks/CU.
__global__ __launch_bounds__(256, 4) void gemm_proj_kernel(
    const short* __restrict__ A, const short* __restrict__ Bt,
    const float* __restrict__ bias, float* __restrict__ out) {
  __shared__ __align__(16) short a_sh[64 * 64];
  __shared__ __align__(16) short b_sh[64 * 64];
  const int tid = threadIdx.x;
  const int w   = tid >> 6, lane = tid & 63, quad = lane >> 4, l16 = lane & 15;
  const int m0  = blockIdx.y * 64, n0 = blockIdx.x * 64;
  const int mw  = (w >> 1) * 32, nw = (w & 1) * 32;
  const int rw  = lane >> 3, seg = lane & 7, gs = seg ^ rw;
  const int sxz = l16 & 7;

  f32x4 acc[2][2];
#pragma unroll
  for (int i = 0; i < 2; ++i)
#pragma unroll
    for (int j = 0; j < 2; ++j) acc[i][j] = {0.f, 0.f, 0.f, 0.f};

  for (int kt = 0; kt < DD; kt += 64) {
    __syncthreads();
    {
      const short* ga = A  + (size_t)(m0 + w * 16 + rw) * DD + kt + gs * 8;
      const short* gb = Bt + (size_t)(n0 + w * 16 + rw) * DD + kt + gs * 8;
#pragma unroll
      for (int i = 0; i < 2; ++i) {
        async16(ga + (size_t)i * 8 * DD, &a_sh[(w * 16 + i * 8) * 64]);
        async16(gb + (size_t)i * 8 * DD, &b_sh[(w * 16 + i * 8) * 64]);
      }
    }
    __syncthreads();
#pragma unroll
    for (int ks = 0; ks < 2; ++ks) {
      const int so = ((ks * 4 + quad) ^ sxz) * 8;
      bf16x8 af0 = *(const bf16x8*)&a_sh[(mw + l16) * 64 + so];
      bf16x8 af1 = *(const bf16x8*)&a_sh[(mw + 16 + l16) * 64 + so];
#pragma unroll
      for (int nt = 0; nt < 2; ++nt) {
        bf16x8 bfr = *(const bf16x8*)&b_sh[(nw + nt * 16 + l16) * 64 + so];
        acc[0][nt] = __builtin_amdgcn_mfma_f32_16x16x32_bf16(af0, bfr, acc[0][nt], 0, 0, 0);
        acc[1][nt] = __builtin_amdgcn_mfma_f32_16x16x32_bf16(af1, bfr, acc[1][nt], 0, 0, 0);
      }
    }
  }

#pragma unroll
  for (int nt = 0; nt < 2; ++nt) {
    const int   n  = n0 + nw + nt * 16 + l16;
    const float bv = bias[n];
#pragma unroll
    for (int mt = 0; mt < 2; ++mt)
#pragma unroll
      for (int r = 0; r < 4; ++r) {
        const int m = m0 + mw + mt * 16 + quad * 4 + r;
        out[(size_t)m * DD + n] = acc[mt][nt][r] + bv;
      }
  }
}

// ---------------------------------------------------------------- launcher
extern "C" void kernel_launch(void* const* d_in, const int* in_sizes, int n_in,
                              void* d_out, int out_size, void* d_ws, size_t ws_size,
                              hipStream_t stream) {
  (void)in_sizes; (void)n_in; (void)out_size; (void)ws_size;
  const float* x  = (const float*)d_in[0];
  const float* Wq = (const float*)d_in[1];
  const float* bq = (const float*)d_in[2];
  const float* Wk = (const float*)d_in[3];
  const float* bk = (const float*)d_in[4];
  const float* Wv = (const float*)d_in[5];
  const float* bv = (const float*)d_in[6];
  const float* Wh = (const float*)d_in[7];
  const float* bh = (const float*)d_in[8];

  short* ws  = (short*)d_ws;
  short* xb  = ws;                              // x bf16 [8192,512]; reused as Op0
  short* wqt = xb  + (size_t)MM * DD;           // Wq^T bf16 [512,512]
  short* wkt = wqt + (size_t)DD * DD;           // (wqt..wvt contiguous = QKV Bt)
  short* wvt = wkt + (size_t)DD * DD;
  short* wht = wvt + (size_t)DD * DD;
  short* qws = wht + (size_t)DD * DD;           // q bf16 [B,H,S,64] (pre-scaled)
  short* kws = qws + (size_t)MM * DD;           // k bf16 [B,H,S,64]
  short* vws = kws + (size_t)MM * DD;           // v^T bf16 [B,H,64,S]
  short* aws = vws + (size_t)MM * DD;           // attn out bf16 [B,S,512]
  short* op1 = aws + (size_t)MM * DD;           // partial O half1 [B,H,S,64]
  float* lpw = (float*)(op1 + (size_t)MM * DD); // partial l [2][B*H*S]

  hipLaunchKernelGGL(prep_kernel, dim3(2048 + 256), dim3(256), 0, stream,
                     x, xb, Wq, Wk, Wv, Wh, wqt, wkt, wvt, wht);

  // q pre-scale: (1/sqrt(64)) * log2(e) so softmax uses exp2 directly
  const float qscale = 1.4426950408889634f / 8.0f;
  hipLaunchKernelGGL(gemm_qkv_kernel, dim3(12, 64), dim3(256), 0, stream,
                     xb, wqt, bq, bk, bv, qws, kws, vws, qscale);

  // Op0 reuses xb (dead after gemm_qkv)
  hipLaunchKernelGGL(attn_kernel, dim3(1024), dim3(256), 0, stream,
                     qws, kws, vws, xb, op1, lpw);
  hipLaunchKernelGGL(attn_combine_kernel, dim3(NB * HH * SS * 8 / 256), dim3(256), 0, stream,
                     xb, op1, lpw, aws);

  hipLaunchKernelGGL(gemm_proj_kernel, dim3(8, 128), dim3(256), 0, stream,
                     aws, wht, bh, (float*)d_out);
}

// Round 2
// 178.244 us; speedup vs baseline: 1.3000x; 1.3000x over previous
//
#include <hip/hip_runtime.h>
#include <stdint.h>

// Problem constants (reference: B=4, S=2048, D=512, H=8, d_head=64)
#define NB  4
#define SS  2048
#define DD  512
#define HH  8
#define DHH 64
#define MM  (NB * SS)   // 8192 rows

typedef __attribute__((ext_vector_type(8))) short bf16x8;  // 8 bf16 in 4 VGPRs
typedef __attribute__((ext_vector_type(4))) float f32x4;   // MFMA C/D frag
typedef __attribute__((ext_vector_type(4))) short s16x4;   // 8 B pack

union fu32 { float f; unsigned u; };
union pfu  { uint4 u; bf16x8 v; };

// fp32 -> bf16 round-to-nearest-even (bit pattern in a short)
static __device__ __forceinline__ short f2bf(float f) {
  fu32 a; a.f = f;
  unsigned u = a.u;
  return (short)((u + 0x7fffu + ((u >> 16) & 1u)) >> 16);
}
static __device__ __forceinline__ float bf2f(short s) {
  fu32 t; t.u = ((unsigned)(unsigned short)s) << 16;
  return t.f;
}

// async global->LDS, 16 B/lane; LDS dest = wave-uniform base + lane*16
static __device__ __forceinline__ void async16(const void* g, void* l) {
  __builtin_amdgcn_global_load_lds(
      (__attribute__((address_space(1))) unsigned*)(void*)g,
      (__attribute__((address_space(3))) unsigned*)l, 16, 0, 0);
}

// ------------------------------- prep: x->bf16 (blocks 0..2047) and
//                                 W[k][n] fp32 -> Wt[n][k] bf16 (2048..2303)
__global__ __launch_bounds__(256) void prep_kernel(
    const float* __restrict__ x, short* __restrict__ xb,
    const float* __restrict__ W0, const float* __restrict__ W1,
    const float* __restrict__ W2, const float* __restrict__ W3,
    short* __restrict__ T0, short* __restrict__ T1,
    short* __restrict__ T2, short* __restrict__ T3) {
  const int bid = blockIdx.x, tid = threadIdx.x;
  if (bid < 2048) {
    int i = (bid * 256 + tid) * 8;
    float4 v0 = *(const float4*)(x + i);
    float4 v1 = *(const float4*)(x + i + 4);
    bf16x8 o;
    o[0] = f2bf(v0.x); o[1] = f2bf(v0.y); o[2] = f2bf(v0.z); o[3] = f2bf(v0.w);
    o[4] = f2bf(v1.x); o[5] = f2bf(v1.y); o[6] = f2bf(v1.z); o[7] = f2bf(v1.w);
    *(bf16x8*)(xb + i) = o;
  } else {
    int z = bid - 2048;                 // 0..255
    int widx = z >> 6, rem = z & 63;
    const float* W = widx == 0 ? W0 : widx == 1 ? W1 : widx == 2 ? W2 : W3;
    short*       T = widx == 0 ? T0 : widx == 1 ? T1 : widx == 2 ? T2 : T3;
    int n  = (rem & 7) * 64 + (tid & 63);
    int k0 = (rem >> 3) * 64 + (tid >> 6) * 16;
    bf16x8 t0, t1;
#pragma unroll
    for (int j = 0; j < 8; ++j) t0[j] = f2bf(W[(size_t)(k0 + j) * DD + n]);
#pragma unroll
    for (int j = 0; j < 8; ++j) t1[j] = f2bf(W[(size_t)(k0 + 8 + j) * DD + n]);
    *(bf16x8*)(T + (size_t)n * DD + k0)     = t0;
    *(bf16x8*)(T + (size_t)n * DD + k0 + 8) = t1;
  }
}

// ---------------------------------------- fused QKV GEMM: 64x128, N = 1536
// grid (12,128) = 1536 blocks -> 4+ blocks/CU for latency overlap across the
// short (8-iter) K-loop.  global_load_lds staging, XOR-swizzled segments.
// Epilogue: q,k -> [B,H,S,64] bf16 (q pre-scaled), v -> [B,H,64,S] bf16.
__global__ __launch_bounds__(256, 4) void gemm_qkv_kernel(
    const short* __restrict__ A, const short* __restrict__ Bt,
    const float* __restrict__ bq, const float* __restrict__ bk,
    const float* __restrict__ bv, short* __restrict__ qout,
    short* __restrict__ kout, short* __restrict__ vtout, float qscale) {
  __shared__ __align__(16) short a_sh[64 * 64];
  __shared__ __align__(16) short b_sh[128 * 64];
  const int tid  = threadIdx.x;
  const int w    = tid >> 6, lane = tid & 63, quad = lane >> 4, l16 = lane & 15;
  const int m0   = blockIdx.y * 64, n0 = blockIdx.x * 128;
  const int mw   = (w >> 1) * 32,   nw = (w & 1) * 64;
  const int rw   = lane >> 3, seg = lane & 7, gs = seg ^ rw;  // row&7 == rw
  const int sxz  = l16 & 7;   // fragment-read swizzle key

  f32x4 acc[2][4];
#pragma unroll
  for (int i = 0; i < 2; ++i)
#pragma unroll
    for (int j = 0; j < 4; ++j) acc[i][j] = {0.f, 0.f, 0.f, 0.f};

  for (int kt = 0; kt < DD; kt += 64) {
    __syncthreads();
    {
      const short* ga = A  + (size_t)(m0 + w * 16 + rw) * DD + kt + gs * 8;
      const short* gb = Bt + (size_t)(n0 + w * 32 + rw) * DD + kt + gs * 8;
#pragma unroll
      for (int i = 0; i < 2; ++i)
        async16(ga + (size_t)i * 8 * DD, &a_sh[(w * 16 + i * 8) * 64]);
#pragma unroll
      for (int i = 0; i < 4; ++i)
        async16(gb + (size_t)i * 8 * DD, &b_sh[(w * 32 + i * 8) * 64]);
    }
    __syncthreads();
#pragma unroll
    for (int ks = 0; ks < 2; ++ks) {
      const int so = ((ks * 4 + quad) ^ sxz) * 8;
      bf16x8 af[2], bfr[4];
#pragma unroll
      for (int mt = 0; mt < 2; ++mt)
        af[mt] = *(const bf16x8*)&a_sh[(mw + mt * 16 + l16) * 64 + so];
#pragma unroll
      for (int nt = 0; nt < 4; ++nt)
        bfr[nt] = *(const bf16x8*)&b_sh[(nw + nt * 16 + l16) * 64 + so];
#pragma unroll
      for (int mt = 0; mt < 2; ++mt)
#pragma unroll
        for (int nt = 0; nt < 4; ++nt)
          acc[mt][nt] = __builtin_amdgcn_mfma_f32_16x16x32_bf16(
              af[mt], bfr[nt], acc[mt][nt], 0, 0, 0);
    }
  }

#pragma unroll
  for (int nt = 0; nt < 4; ++nt) {
    const int n   = n0 + nw + nt * 16 + l16;   // 0..1535
    const int sg  = n >> 9, n9 = n & 511, h = n9 >> 6, d = n & 63;
    const float bval = (sg == 0 ? bq : sg == 1 ? bk : bv)[n9];
    const float scl  = (sg == 0) ? qscale : 1.0f;
#pragma unroll
    for (int mt = 0; mt < 2; ++mt) {
      const int mb = m0 + mw + mt * 16 + quad * 4;   // C row = quad*4 + r
      const int bi = mb >> 11, s = mb & (SS - 1);
      if (sg == 2) {
        s16x4 pk;
#pragma unroll
        for (int r = 0; r < 4; ++r) pk[r] = f2bf(acc[mt][nt][r] + bval);
        *(s16x4*)&vtout[((size_t)(bi * HH + h) * DHH + d) * SS + s] = pk;
      } else {
        short* o = (sg == 0) ? qout : kout;
        const size_t base = ((size_t)(bi * HH + h) * SS + s) * DHH + d;
#pragma unroll
        for (int r = 0; r < 4; ++r)
          o[base + (size_t)r * DHH] = f2bf((acc[mt][nt][r] + bval) * scl);
      }
    }
  }
}

// ----------------------------------------------- flash attention, key-split
// S^T = K·Q^T; P fragments assembled in registers (pack -> ^16 exchange ->
// select -> 4 ds_bpermute); softmax denominator via MFMA-vs-ones (C-layout
// matches O -> zero-shuffle normalization).  Raw v_exp_f32 via
// __builtin_amdgcn_exp2f (scores bounded, no range fixup needed).
// T3-minimum 2-phase pipeline: KV tiles of 64 keys, double-buffered in LDS
// (2 x 8 KB K + 2 x 8 KB V^T = 32 KB, occupancy preserved at 4 blocks/CU).
// Next tile's global_load_lds is issued BEFORE the current tile's compute;
// the single __syncthreads() per tile drains a vmcnt that has had the whole
// compute phase (~28 MFMA + 32 exp2) to complete.  No reg staging -> no
// scratch (the round-1 regression).
__global__ __launch_bounds__(256, 4) void attn_kernel(
    const short* __restrict__ Qa, const short* __restrict__ Ka,
    const short* __restrict__ Vt, short* __restrict__ Op0,
    short* __restrict__ Op1, float* __restrict__ lpw) {
  __shared__ __align__(16) short k_sh[2][64 * 64];   // K tiles, swizzled segs
  __shared__ __align__(16) short vt_sh[2][64 * 64];  // V^T tiles, swizzled segs

  const int tid  = threadIdx.x;
  const int w    = tid >> 6, lane = tid & 63, quad = lane >> 4, l16 = lane & 15;
  // XCD-aware decode: xcd = n&7 (dispatch heuristic), 8 groups x 16 qt per XCD
  const int n    = blockIdx.x;
  const int grp  = (n & 7) * 8 + (n >> 7);   // (b,h,half) group, 0..63
  const int qt_b = (n >> 3) & 15;
  const int half = grp & 1, h = (grp >> 1) & 7, b = grp >> 4;
  const int q0   = qt_b * 128;
  const int rw = lane >> 3, seg = lane & 7, gs = seg ^ rw;  // row&7 == rw
  const int sxz = l16 & 7;
  const size_t base = (size_t)(b * HH + h) * SS * DHH;
  const short* Qg = Qa + base + (size_t)(q0 + w * 32) * DHH;
  const short* Kg = Ka + base;
  const short* Vg = Vt + base;           // [64][S]

  // Q fragments (usable as A or B operand: same lane map)
  bf16x8 qf[2][2];
#pragma unroll
  for (int mt = 0; mt < 2; ++mt)
#pragma unroll
    for (int ks = 0; ks < 2; ++ks)
      qf[mt][ks] = *(const bf16x8*)(Qg + (size_t)(mt * 16 + l16) * DHH + ks * 32 + quad * 8);

  bf16x8 ones;
#pragma unroll
  for (int j = 0; j < 8; ++j) ones[j] = (short)0x3F80;   // bf16 1.0

  f32x4 o_acc[2][4];
#pragma unroll
  for (int qt = 0; qt < 2; ++qt)
#pragma unroll
    for (int dt = 0; dt < 4; ++dt) o_acc[qt][dt] = {0.f, 0.f, 0.f, 0.f};
  f32x4 l_acc[2] = {{0.f, 0.f, 0.f, 0.f}, {0.f, 0.f, 0.f, 0.f}};

  // bpermute byte-addresses for the verified cross-quad gather:
  // dwords 0/1 pull from src_quad = (quad&1)*2 + (quad>>1); dwords 2/3 from ^1
  const int addrA = ((((quad & 1) << 1) + (quad >> 1)) * 16 + l16) * 4;
  const int addrB = addrA ^ 64;
  const bool qeven = (quad & 1) == 0;

  const int kstart = half * (SS / 2);
  const int kend   = kstart + SS / 2;

  // stage a 64-key K tile + V^T tile into buffer bsel (global_load_lds,
  // per-lane pre-swizzled global source, linear LDS dest = base + lane*16).
  // Each wave covers 16 rows (K) and 16 d-rows (V); row&7 == rw for both.
  auto stage = [&](int bsel, int kb) {
    const short* gk = Kg + (size_t)(kb + w * 16 + rw) * DHH + gs * 8;
#pragma unroll
    for (int i = 0; i < 2; ++i)
      async16(gk + (size_t)i * 8 * DHH, &k_sh[bsel][(w * 16 + i * 8) * 64]);
#pragma unroll
    for (int i = 0; i < 2; ++i) {
      const int d = w * 16 + i * 8 + rw;
      async16(Vg + (size_t)d * SS + kb + gs * 8,
              &vt_sh[bsel][(w * 16 + i * 8) * 64]);
    }
  };

  stage(0, kstart);
  __syncthreads();
  int cur = 0;

  for (int kb = kstart; kb < kend; kb += 64) {
    // issue next tile's loads first; latency hides under this tile's compute
    if (kb + 64 < kend) stage(cur ^ 1, kb + 64);

    // 2 chunks of 32 keys: QK^T (2 tiles) -> exp2/pack -> permute -> PV + l
#pragma unroll
    for (int ck = 0; ck < 2; ++ck) {
      uint2 pk[2][2];   // [qt][tile]
#pragma unroll
      for (int t = 0; t < 2; ++t) {
        const int knt = ck * 2 + t;
        bf16x8 kf0 = *(const bf16x8*)&k_sh[cur][(knt * 16 + l16) * 64 + ((0 * 4 + quad) ^ sxz) * 8];
        bf16x8 kf1 = *(const bf16x8*)&k_sh[cur][(knt * 16 + l16) * 64 + ((1 * 4 + quad) ^ sxz) * 8];
#pragma unroll
        for (int qt = 0; qt < 2; ++qt) {
          f32x4 s = {0.f, 0.f, 0.f, 0.f};
          s = __builtin_amdgcn_mfma_f32_16x16x32_bf16(kf0, qf[qt][0], s, 0, 0, 0);
          s = __builtin_amdgcn_mfma_f32_16x16x32_bf16(kf1, qf[qt][1], s, 0, 0, 0);
          fu32 e0, e1, e2, e3;
          e0.f = __builtin_amdgcn_exp2f(s[0]);
          e1.f = __builtin_amdgcn_exp2f(s[1]);
          e2.f = __builtin_amdgcn_exp2f(s[2]);
          e3.f = __builtin_amdgcn_exp2f(s[3]);
          pk[qt][t].x = __builtin_amdgcn_perm(e1.u, e0.u, 0x07060302u);
          pk[qt][t].y = __builtin_amdgcn_perm(e3.u, e2.u, 0x07060302u);
        }
      }
      // assemble A-layout P fragments (32 keys) in registers
      pfu pf[2];
#pragma unroll
      for (int qt = 0; qt < 2; ++qt) {
        // pre-exchange pk[1] across quad^1 (lane^16)
        unsigned p1x = (unsigned)__shfl_xor((int)pk[qt][1].x, 16);
        unsigned p1y = (unsigned)__shfl_xor((int)pk[qt][1].y, 16);
        // per-dword contributions (source-lane side)
        unsigned v0x = qeven ? pk[qt][0].x : p1x;
        unsigned v0y = qeven ? pk[qt][0].y : p1y;
        unsigned v2x = qeven ? p1x : pk[qt][0].x;
        unsigned v2y = qeven ? p1y : pk[qt][0].y;
        pf[qt].u.x = (unsigned)__builtin_amdgcn_ds_bpermute(addrA, (int)v0x);
        pf[qt].u.y = (unsigned)__builtin_amdgcn_ds_bpermute(addrA, (int)v0y);
        pf[qt].u.z = (unsigned)__builtin_amdgcn_ds_bpermute(addrB, (int)v2x);
        pf[qt].u.w = (unsigned)__builtin_amdgcn_ds_bpermute(addrB, (int)v2y);
        l_acc[qt] = __builtin_amdgcn_mfma_f32_16x16x32_bf16(pf[qt].v, ones, l_acc[qt], 0, 0, 0);
      }
#pragma unroll
      for (int dt = 0; dt < 4; ++dt) {
        bf16x8 vf = *(const bf16x8*)&vt_sh[cur][(dt * 16 + l16) * 64 + ((ck * 4 + quad) ^ sxz) * 8];
        o_acc[0][dt] = __builtin_amdgcn_mfma_f32_16x16x32_bf16(pf[0].v, vf, o_acc[0][dt], 0, 0, 0);
        o_acc[1][dt] = __builtin_amdgcn_mfma_f32_16x16x32_bf16(pf[1].v, vf, o_acc[1][dt], 0, 0, 0);
      }
    }

    __syncthreads();   // drains this tile's prefetch (in flight during compute)
    cur ^= 1;
  }

  // epilogue: l_acc is in the same C-layout as o_acc (row = query quad*4+r,
  // value replicated across l16) -> zero-shuffle normalization.
  short* Op = half ? Op1 : Op0;
#pragma unroll
  for (int qt = 0; qt < 2; ++qt) {
#pragma unroll
    for (int r = 0; r < 4; ++r) {
      const int qg = q0 + w * 32 + qt * 16 + quad * 4 + r;
      const size_t row = (size_t)(b * HH + h) * SS + qg;
      if (l16 == 0)
        lpw[(size_t)half * (NB * HH * SS) + row] = l_acc[qt][r];
      const float inv = __builtin_amdgcn_rcpf(l_acc[qt][r]);
#pragma unroll
      for (int dt = 0; dt < 4; ++dt)
        Op[row * DHH + dt * 16 + l16] = f2bf(o_acc[qt][dt][r] * inv);
    }
  }
}

// ------------------------------------- merge the two key-halves -> aws bf16
__global__ void attn_combine_kernel(const short* __restrict__ Op0,
                                    const short* __restrict__ Op1,
                                    const float* __restrict__ lpw,
                                    short* __restrict__ aws) {
  int idx  = blockIdx.x * 256 + threadIdx.x;   // over B*H*S*8 segments
  int dsg  = idx & 7;
  int row  = idx >> 3;                         // (b*H + h)*S + q
  int q    = row & (SS - 1);
  int bh   = row >> 11, h = bh & 7, b = bh >> 3;
  float l1 = lpw[row], l2 = lpw[NB * HH * SS + row];
  float inv = 1.f / (l1 + l2);
  float w1 = l1 * inv, w2 = l2 * inv;
  bf16x8 a = *(const bf16x8*)&Op0[(size_t)row * DHH + dsg * 8];
  bf16x8 c = *(const bf16x8*)&Op1[(size_t)row * DHH + dsg * 8];
  bf16x8 o;
#pragma unroll
  for (int j = 0; j < 8; ++j) o[j] = f2bf(w1 * bf2f(a[j]) + w2 * bf2f(c[j]));
  *(bf16x8*)&aws[((size_t)(b * SS + q)) * DD + h * DHH + dsg * 8] = o;
}

// ------------------------------------------- output projection: 64x64 tile
// grid (8,128) = 1024 blocks -> 4 blocks/CU.
__global__ __launch_bounds__(256, 4) void gemm_proj_kernel(
    const short* __restrict__ A, const short* __restrict__ Bt,
    const float* __restrict__ bias, float* __restrict__ out) {
  __shared__ __align__(16) short a_sh[64 * 64];
  __shared__ __align__(16) short b_sh[64 * 64];
  const int tid = threadIdx.x;
  const int w   = tid >> 6, lane = tid & 63, quad = lane >> 4, l16 = lane & 15;
  const int m0  = blockIdx.y * 64, n0 = blockIdx.x * 64;
  const int mw  = (w >> 1) * 32, nw = (w & 1) * 32;
  const int rw  = lane >> 3, seg = lane & 7, gs = seg ^ rw;
  const int sxz = l16 & 7;

  f32x4 acc[2][2];
#pragma unroll
  for (int i = 0; i < 2; ++i)
#pragma unroll
    for (int j = 0; j < 2; ++j) acc[i][j] = {0.f, 0.f, 0.f, 0.f};

  for (int kt = 0; kt < DD; kt += 64) {
    __syncthreads();
    {
      const short* ga = A  + (size_t)(m0 + w * 16 + rw) * DD + kt + gs * 8;
      const short* gb = Bt + (size_t)(n0 + w * 16 + rw) * DD + kt + gs * 8;
#pragma unroll
      for (int i = 0; i < 2; ++i) {
        async16(ga + (size_t)i * 8 * DD, &a_sh[(w * 16 + i * 8) * 64]);
        async16(gb + (size_t)i * 8 * DD, &b_sh[(w * 16 + i * 8) * 64]);
      }
    }
    __syncthreads();
#pragma unroll
    for (int ks = 0; ks < 2; ++ks) {
      const int so = ((ks * 4 + quad) ^ sxz) * 8;
      bf16x8 af0 = *(const bf16x8*)&a_sh[(mw + l16) * 64 + so];
      bf16x8 af1 = *(const bf16x8*)&a_sh[(mw + 16 + l16) * 64 + so];
#pragma unroll
      for (int nt = 0; nt < 2; ++nt) {
        bf16x8 bfr = *(const bf16x8*)&b_sh[(nw + nt * 16 + l16) * 64 + so];
        acc[0][nt] = __builtin_amdgcn_mfma_f32_16x16x32_bf16(af0, bfr, acc[0][nt], 0, 0, 0);
        acc[1][nt] = __builtin_amdgcn_mfma_f32_16x16x32_bf16(af1, bfr, acc[1][nt], 0, 0, 0);
      }
    }
  }

#pragma unroll
  for (int nt = 0; nt < 2; ++nt) {
    const int   n  = n0 + nw + nt * 16 + l16;
    const float bv = bias[n];
#pragma unroll
    for (int mt = 0; mt < 2; ++mt)
#pragma unroll
      for (int r = 0; r < 4; ++r) {
        const int m = m0 + mw + mt * 16 + quad * 4 + r;
        out[(size_t)m * DD + n] = acc[mt][nt][r] + bv;
      }
  }
}

// ---------------------------------------------------------------- launcher
extern "C" void kernel_launch(void* const* d_in, const int* in_sizes, int n_in,
                              void* d_out, int out_size, void* d_ws, size_t ws_size,
                              hipStream_t stream) {
  (void)in_sizes; (void)n_in; (void)out_size; (void)ws_size;
  const float* x  = (const float*)d_in[0];
  const float* Wq = (const float*)d_in[1];
  const float* bq = (const float*)d_in[2];
  const float* Wk = (const float*)d_in[3];
  const float* bk = (const float*)d_in[4];
  const float* Wv = (const float*)d_in[5];
  const float* bv = (const float*)d_in[6];
  const float* Wh = (const float*)d_in[7];
  const float* bh = (const float*)d_in[8];

  short* ws  = (short*)d_ws;
  short* xb  = ws;                              // x bf16 [8192,512]; reused as Op0
  short* wqt = xb  + (size_t)MM * DD;           // Wq^T bf16 [512,512]
  short* wkt = wqt + (size_t)DD * DD;           // (wqt..wvt contiguous = QKV Bt)
  short* wvt = wkt + (size_t)DD * DD;
  short* wht = wvt + (size_t)DD * DD;
  short* qws = wht + (size_t)DD * DD;           // q bf16 [B,H,S,64] (pre-scaled)
  short* kws = qws + (size_t)MM * DD;           // k bf16 [B,H,S,64]
  short* vws = kws + (size_t)MM * DD;           // v^T bf16 [B,H,64,S]
  short* aws = vws + (size_t)MM * DD;           // attn out bf16 [B,S,512]
  short* op1 = aws + (size_t)MM * DD;           // partial O half1 [B,H,S,64]
  float* lpw = (float*)(op1 + (size_t)MM * DD); // partial l [2][B*H*S]

  hipLaunchKernelGGL(prep_kernel, dim3(2048 + 256), dim3(256), 0, stream,
                     x, xb, Wq, Wk, Wv, Wh, wqt, wkt, wvt, wht);

  // q pre-scale: (1/sqrt(64)) * log2(e) so softmax uses exp2 directly
  const float qscale = 1.4426950408889634f / 8.0f;
  hipLaunchKernelGGL(gemm_qkv_kernel, dim3(12, 128), dim3(256), 0, stream,
                     xb, wqt, bq, bk, bv, qws, kws, vws, qscale);

  // Op0 reuses xb (dead after gemm_qkv)
  hipLaunchKernelGGL(attn_kernel, dim3(1024), dim3(256), 0, stream,
                     qws, kws, vws, xb, op1, lpw);
  hipLaunchKernelGGL(attn_combine_kernel, dim3(NB * HH * SS * 8 / 256), dim3(256), 0, stream,
                     xb, op1, lpw, aws);

  hipLaunchKernelGGL(gemm_proj_kernel, dim3(8, 128), dim3(256), 0, stream,
                     aws, wht, bh, (float*)d_out);
}

// Round 3
// 164.768 us; speedup vs baseline: 1.4063x; 1.0818x over previous
//
#include <hip/hip_runtime.h>
#include <stdint.h>

// Problem constants (reference: B=4, S=2048, D=512, H=8, d_head=64)
#define NB  4
#define SS  2048
#define DD  512
#define HH  8
#define DHH 64
#define MM  (NB * SS)   // 8192 rows

typedef __attribute__((ext_vector_type(8))) short bf16x8;   // 8 bf16 in 4 VGPRs
typedef __attribute__((ext_vector_type(4))) float f32x4;    // 16x16 MFMA C/D
typedef __attribute__((ext_vector_type(16))) float f32x16;  // 32x32 MFMA C/D
typedef __attribute__((ext_vector_type(4))) short s16x4;    // 8 B pack

union fu32 { float f; unsigned u; };
union pfu  { uint4 u; bf16x8 v; };

// fp32 -> bf16 round-to-nearest-even (bit pattern in a short)
static __device__ __forceinline__ short f2bf(float f) {
  fu32 a; a.f = f;
  unsigned u = a.u;
  return (short)((u + 0x7fffu + ((u >> 16) & 1u)) >> 16);
}
static __device__ __forceinline__ float bf2f(short s) {
  fu32 t; t.u = ((unsigned)(unsigned short)s) << 16;
  return t.f;
}

// packed f32x2 -> bf16x2 (RNE) — no builtin on gfx950, inline asm (m240)
static __device__ __forceinline__ unsigned cvt_pk_bf16(float lo, float hi) {
  unsigned r;
  asm("v_cvt_pk_bf16_f32 %0, %1, %2" : "=v"(r) : "v"(lo), "v"(hi));
  return r;
}
// v_permlane32_swap_b32: a <- [a_lo, b_lo], b <- [a_hi, b_hi]  (VALU, not DS)
static __device__ __forceinline__ void permlane32_swap(unsigned& a, unsigned& b) {
  asm("v_permlane32_swap_b32 %0, %1" : "+v"(a), "+v"(b));
}

// async global->LDS, 16 B/lane; LDS dest = wave-uniform base + lane*16
static __device__ __forceinline__ void async16(const void* g, void* l) {
  __builtin_amdgcn_global_load_lds(
      (__attribute__((address_space(1))) unsigned*)(void*)g,
      (__attribute__((address_space(3))) unsigned*)l, 16, 0, 0);
}

// ------------------------------- prep: x->bf16 (blocks 0..2047) and
//                                 W[k][n] fp32 -> Wt[n][k] bf16 (2048..2303)
__global__ __launch_bounds__(256) void prep_kernel(
    const float* __restrict__ x, short* __restrict__ xb,
    const float* __restrict__ W0, const float* __restrict__ W1,
    const float* __restrict__ W2, const float* __restrict__ W3,
    short* __restrict__ T0, short* __restrict__ T1,
    short* __restrict__ T2, short* __restrict__ T3) {
  const int bid = blockIdx.x, tid = threadIdx.x;
  if (bid < 2048) {
    int i = (bid * 256 + tid) * 8;
    float4 v0 = *(const float4*)(x + i);
    float4 v1 = *(const float4*)(x + i + 4);
    bf16x8 o;
    o[0] = f2bf(v0.x); o[1] = f2bf(v0.y); o[2] = f2bf(v0.z); o[3] = f2bf(v0.w);
    o[4] = f2bf(v1.x); o[5] = f2bf(v1.y); o[6] = f2bf(v1.z); o[7] = f2bf(v1.w);
    *(bf16x8*)(xb + i) = o;
  } else {
    int z = bid - 2048;                 // 0..255
    int widx = z >> 6, rem = z & 63;
    const float* W = widx == 0 ? W0 : widx == 1 ? W1 : widx == 2 ? W2 : W3;
    short*       T = widx == 0 ? T0 : widx == 1 ? T1 : widx == 2 ? T2 : T3;
    int n  = (rem & 7) * 64 + (tid & 63);
    int k0 = (rem >> 3) * 64 + (tid >> 6) * 16;
    bf16x8 t0, t1;
#pragma unroll
    for (int j = 0; j < 8; ++j) t0[j] = f2bf(W[(size_t)(k0 + j) * DD + n]);
#pragma unroll
    for (int j = 0; j < 8; ++j) t1[j] = f2bf(W[(size_t)(k0 + 8 + j) * DD + n]);
    *(bf16x8*)(T + (size_t)n * DD + k0)     = t0;
    *(bf16x8*)(T + (size_t)n * DD + k0 + 8) = t1;
  }
}

// ---------------------------------------- fused QKV GEMM: 64x128, N = 1536
// grid (12,128) = 1536 blocks -> 4+ blocks/CU for latency overlap across the
// short (8-iter) K-loop.  global_load_lds staging, XOR-swizzled segments.
// Epilogue: q,k -> [B,H,S,64] bf16 (q pre-scaled), v -> [B,H,64,S] bf16.
__global__ __launch_bounds__(256, 4) void gemm_qkv_kernel(
    const short* __restrict__ A, const short* __restrict__ Bt,
    const float* __restrict__ bq, const float* __restrict__ bk,
    const float* __restrict__ bv, short* __restrict__ qout,
    short* __restrict__ kout, short* __restrict__ vtout, float qscale) {
  __shared__ __align__(16) short a_sh[64 * 64];
  __shared__ __align__(16) short b_sh[128 * 64];
  const int tid  = threadIdx.x;
  const int w    = tid >> 6, lane = tid & 63, quad = lane >> 4, l16 = lane & 15;
  const int m0   = blockIdx.y * 64, n0 = blockIdx.x * 128;
  const int mw   = (w >> 1) * 32,   nw = (w & 1) * 64;
  const int rw   = lane >> 3, seg = lane & 7, gs = seg ^ rw;  // row&7 == rw
  const int sxz  = l16 & 7;   // fragment-read swizzle key

  f32x4 acc[2][4];
#pragma unroll
  for (int i = 0; i < 2; ++i)
#pragma unroll
    for (int j = 0; j < 4; ++j) acc[i][j] = {0.f, 0.f, 0.f, 0.f};

  for (int kt = 0; kt < DD; kt += 64) {
    __syncthreads();
    {
      const short* ga = A  + (size_t)(m0 + w * 16 + rw) * DD + kt + gs * 8;
      const short* gb = Bt + (size_t)(n0 + w * 32 + rw) * DD + kt + gs * 8;
#pragma unroll
      for (int i = 0; i < 2; ++i)
        async16(ga + (size_t)i * 8 * DD, &a_sh[(w * 16 + i * 8) * 64]);
#pragma unroll
      for (int i = 0; i < 4; ++i)
        async16(gb + (size_t)i * 8 * DD, &b_sh[(w * 32 + i * 8) * 64]);
    }
    __syncthreads();
#pragma unroll
    for (int ks = 0; ks < 2; ++ks) {
      const int so = ((ks * 4 + quad) ^ sxz) * 8;
      bf16x8 af[2], bfr[4];
#pragma unroll
      for (int mt = 0; mt < 2; ++mt)
        af[mt] = *(const bf16x8*)&a_sh[(mw + mt * 16 + l16) * 64 + so];
#pragma unroll
      for (int nt = 0; nt < 4; ++nt)
        bfr[nt] = *(const bf16x8*)&b_sh[(nw + nt * 16 + l16) * 64 + so];
#pragma unroll
      for (int mt = 0; mt < 2; ++mt)
#pragma unroll
        for (int nt = 0; nt < 4; ++nt)
          acc[mt][nt] = __builtin_amdgcn_mfma_f32_16x16x32_bf16(
              af[mt], bfr[nt], acc[mt][nt], 0, 0, 0);
    }
  }

#pragma unroll
  for (int nt = 0; nt < 4; ++nt) {
    const int n   = n0 + nw + nt * 16 + l16;   // 0..1535
    const int sg  = n >> 9, n9 = n & 511, h = n9 >> 6, d = n & 63;
    const float bval = (sg == 0 ? bq : sg == 1 ? bk : bv)[n9];
    const float scl  = (sg == 0) ? qscale : 1.0f;
#pragma unroll
    for (int mt = 0; mt < 2; ++mt) {
      const int mb = m0 + mw + mt * 16 + quad * 4;   // C row = quad*4 + r
      const int bi = mb >> 11, s = mb & (SS - 1);
      if (sg == 2) {
        s16x4 pk;
#pragma unroll
        for (int r = 0; r < 4; ++r) pk[r] = f2bf(acc[mt][nt][r] + bval);
        *(s16x4*)&vtout[((size_t)(bi * HH + h) * DHH + d) * SS + s] = pk;
      } else {
        short* o = (sg == 0) ? qout : kout;
        const size_t base = ((size_t)(bi * HH + h) * SS + s) * DHH + d;
#pragma unroll
        for (int r = 0; r < 4; ++r)
          o[base + (size_t)r * DHH] = f2bf((acc[mt][nt][r] + bval) * scl);
      }
    }
  }
}

// ----------------------------------------------- flash attention, key-split
// 32x32x16 MFMA restructure (T12): S^T = K·Q^T via mfma_32x32x16 -> C-layout
// has query = lane&31, keys in the 16 accumulator regs.  P -> bf16 A-operand
// assembly is now ALL VALU: 8 v_cvt_pk_bf16_f32 + 4 v_permlane32_swap_b32
// per 32-key chunk (replaces 8 ds_bpermute + 4 shfl = the 2^21 bank-conflict
// source and ~half the DS-pipe load).  Softmax denominator via MFMA-vs-ones
// (same C-layout as O -> zero-shuffle normalization).  64-key LDS tiles,
// double-buffered, global_load_lds staging with XOR-swizzled segments.
__global__ __launch_bounds__(256, 4) void attn_kernel(
    const short* __restrict__ Qa, const short* __restrict__ Ka,
    const short* __restrict__ Vt, short* __restrict__ Op0,
    short* __restrict__ Op1, float* __restrict__ lpw) {
  __shared__ __align__(16) short k_sh[2][64 * 64];   // K tiles, swizzled segs
  __shared__ __align__(16) short vt_sh[2][64 * 64];  // V^T tiles, swizzled segs

  const int tid  = threadIdx.x;
  const int w    = tid >> 6, lane = tid & 63;
  const int l32  = lane & 31, hl = lane >> 5;
  // XCD-aware decode: xcd = n&7 (dispatch heuristic), 8 groups x 16 qt per XCD
  const int n    = blockIdx.x;
  const int grp  = (n & 7) * 8 + (n >> 7);   // (b,h,half) group, 0..63
  const int qt_b = (n >> 3) & 15;
  const int half = grp & 1, h = (grp >> 1) & 7, b = grp >> 4;
  const int q0   = qt_b * 128;
  const int rw = lane >> 3, seg = lane & 7, gs = seg ^ rw;  // row&7 == rw
  const size_t base = (size_t)(b * HH + h) * SS * DHH;
  const short* Qg = Qa + base + (size_t)(q0 + w * 32) * DHH;
  const short* Kg = Ka + base;
  const short* Vg = Vt + base;           // [64][S]

  // Q as B-operand of 32x32x16: lane holds col(query)=l32, k(d)=ds*16+hl*8+j
  bf16x8 qf[4];
#pragma unroll
  for (int ds = 0; ds < 4; ++ds)
    qf[ds] = *(const bf16x8*)(Qg + (size_t)l32 * DHH + ds * 16 + hl * 8);

  bf16x8 ones;
#pragma unroll
  for (int j = 0; j < 8; ++j) ones[j] = (short)0x3F80;   // bf16 1.0

  f32x16 o_acc[2];   // O[32q][64d]: dt-tile d = dt*32 + l32, rows = regs
  f32x16 l_acc;      // same C-layout rows, replicated across lanes
#pragma unroll
  for (int i = 0; i < 16; ++i) { o_acc[0][i] = 0.f; o_acc[1][i] = 0.f; l_acc[i] = 0.f; }

  const int kstart = half * (SS / 2);
  const int kend   = kstart + SS / 2;

  // stage a 64-key K tile + V^T tile into buffer bsel (global_load_lds,
  // per-lane pre-swizzled global source, linear LDS dest = base + lane*16).
  auto stage = [&](int bsel, int kb) {
    const short* gk = Kg + (size_t)(kb + w * 16 + rw) * DHH + gs * 8;
#pragma unroll
    for (int i = 0; i < 2; ++i)
      async16(gk + (size_t)i * 8 * DHH, &k_sh[bsel][(w * 16 + i * 8) * 64]);
#pragma unroll
    for (int i = 0; i < 2; ++i) {
      const int d = w * 16 + i * 8 + rw;
      async16(Vg + (size_t)d * SS + kb + gs * 8,
              &vt_sh[bsel][(w * 16 + i * 8) * 64]);
    }
  };

  stage(0, kstart);
  __syncthreads();
  int cur = 0;

  for (int kb = kstart; kb < kend; kb += 64) {
    // issue next tile's loads first; latency hides under this tile's compute
    if (kb + 64 < kend) stage(cur ^ 1, kb + 64);

    // 2 chunks of 32 keys
#pragma unroll
    for (int ck = 0; ck < 2; ++ck) {
      // K as A-operand: lane holds row(key)=ck*32+l32, k(d)=ds*16+hl*8+j
      const int krow = ck * 32 + l32;
      bf16x8 kf[4];
#pragma unroll
      for (int ds = 0; ds < 4; ++ds) {
        const int sseg = (ds * 2 + hl) ^ (krow & 7);
        kf[ds] = *(const bf16x8*)&k_sh[cur][krow * 64 + sseg * 8];
      }
      f32x16 s;
#pragma unroll
      for (int i = 0; i < 16; ++i) s[i] = 0.f;
#pragma unroll
      for (int ds = 0; ds < 4; ++ds)
        s = __builtin_amdgcn_mfma_f32_32x32x16_bf16(kf[ds], qf[ds], s, 0, 0, 0);

      // exp2 (q pre-scaled by log2e/8) then pack to bf16 pairs
#pragma unroll
      for (int i = 0; i < 16; ++i) s[i] = __builtin_amdgcn_exp2f(s[i]);
      // reg r holds key (r&3) + 8*(r>>2) + 4*hl for query col l32
      unsigned wpk[8];
#pragma unroll
      for (int i = 0; i < 8; ++i) wpk[i] = cvt_pk_bf16(s[2 * i], s[2 * i + 1]);
      // half-swap: after these, {wpk0..3} = A-frag keys 0-15, {wpk4..7} = 16-31
      permlane32_swap(wpk[0], wpk[2]);
      permlane32_swap(wpk[1], wpk[3]);
      permlane32_swap(wpk[4], wpk[6]);
      permlane32_swap(wpk[5], wpk[7]);
      pfu a0, a1;
      a0.u.x = wpk[0]; a0.u.y = wpk[1]; a0.u.z = wpk[2]; a0.u.w = wpk[3];
      a1.u.x = wpk[4]; a1.u.y = wpk[5]; a1.u.z = wpk[6]; a1.u.w = wpk[7];

      l_acc = __builtin_amdgcn_mfma_f32_32x32x16_bf16(a0.v, ones, l_acc, 0, 0, 0);
      l_acc = __builtin_amdgcn_mfma_f32_32x32x16_bf16(a1.v, ones, l_acc, 0, 0, 0);

      // PV: V as B-operand: lane col(d)=dt*32+l32, k(key)=ck*32+ks*16+hl*8+j
#pragma unroll
      for (int dt = 0; dt < 2; ++dt) {
        const int drow = dt * 32 + l32;
#pragma unroll
        for (int ks = 0; ks < 2; ++ks) {
          const int sseg = (ck * 4 + ks * 2 + hl) ^ (drow & 7);
          bf16x8 vf = *(const bf16x8*)&vt_sh[cur][drow * 64 + sseg * 8];
          o_acc[dt] = __builtin_amdgcn_mfma_f32_32x32x16_bf16(
              ks == 0 ? a0.v : a1.v, vf, o_acc[dt], 0, 0, 0);
        }
      }
    }

    __syncthreads();   // drains this tile's prefetch (in flight during compute)
    cur ^= 1;
  }

  // epilogue: l_acc rows = query regs, same map as o_acc -> zero-shuffle norm.
  short* Op = half ? Op1 : Op0;
#pragma unroll
  for (int r = 0; r < 16; ++r) {
    const int qg = q0 + w * 32 + (r & 3) + 8 * (r >> 2) + 4 * hl;
    const size_t row = (size_t)(b * HH + h) * SS + qg;
    if (l32 == 0)
      lpw[(size_t)half * (NB * HH * SS) + row] = l_acc[r];
    const float inv = __builtin_amdgcn_rcpf(l_acc[r]);
#pragma unroll
    for (int dt = 0; dt < 2; ++dt)
      Op[row * DHH + dt * 32 + l32] = f2bf(o_acc[dt][r] * inv);
  }
}

// ------------------------------------- merge the two key-halves -> aws bf16
__global__ void attn_combine_kernel(const short* __restrict__ Op0,
                                    const short* __restrict__ Op1,
                                    const float* __restrict__ lpw,
                                    short* __restrict__ aws) {
  int idx  = blockIdx.x * 256 + threadIdx.x;   // over B*H*S*8 segments
  int dsg  = idx & 7;
  int row  = idx >> 3;                         // (b*H + h)*S + q
  int q    = row & (SS - 1);
  int bh   = row >> 11, h = bh & 7, b = bh >> 3;
  float l1 = lpw[row], l2 = lpw[NB * HH * SS + row];
  float inv = 1.f / (l1 + l2);
  float w1 = l1 * inv, w2 = l2 * inv;
  bf16x8 a = *(const bf16x8*)&Op0[(size_t)row * DHH + dsg * 8];
  bf16x8 c = *(const bf16x8*)&Op1[(size_t)row * DHH + dsg * 8];
  bf16x8 o;
#pragma unroll
  for (int j = 0; j < 8; ++j) o[j] = f2bf(w1 * bf2f(a[j]) + w2 * bf2f(c[j]));
  *(bf16x8*)&aws[((size_t)(b * SS + q)) * DD + h * DHH + dsg * 8] = o;
}

// ------------------------------------------- output projection: 64x64 tile
// grid (8,128) = 1024 blocks -> 4 blocks/CU.
__global__ __launch_bounds__(256, 4) void gemm_proj_kernel(
    const short* __restrict__ A, const short* __restrict__ Bt,
    const float* __restrict__ bias, float* __restrict__ out) {
  __shared__ __align__(16) short a_sh[64 * 64];
  __shared__ __align__(16) short b_sh[64 * 64];
  const int tid = threadIdx.x;
  const int w   = tid >> 6, lane = tid & 63, quad = lane >> 4, l16 = lane & 15;
  const int m0  = blockIdx.y * 64, n0 = blockIdx.x * 64;
  const int mw  = (w >> 1) * 32, nw = (w & 1) * 32;
  const int rw  = lane >> 3, seg = lane & 7, gs = seg ^ rw;
  const int sxz = l16 & 7;

  f32x4 acc[2][2];
#pragma unroll
  for (int i = 0; i < 2; ++i)
#pragma unroll
    for (int j = 0; j < 2; ++j) acc[i][j] = {0.f, 0.f, 0.f, 0.f};

  for (int kt = 0; kt < DD; kt += 64) {
    __syncthreads();
    {
      const short* ga = A  + (size_t)(m0 + w * 16 + rw) * DD + kt + gs * 8;
      const short* gb = Bt + (size_t)(n0 + w * 16 + rw) * DD + kt + gs * 8;
#pragma unroll
      for (int i = 0; i < 2; ++i) {
        async16(ga + (size_t)i * 8 * DD, &a_sh[(w * 16 + i * 8) * 64]);
        async16(gb + (size_t)i * 8 * DD, &b_sh[(w * 16 + i * 8) * 64]);
      }
    }
    __syncthreads();
#pragma unroll
    for (int ks = 0; ks < 2; ++ks) {
      const int so = ((ks * 4 + quad) ^ sxz) * 8;
      bf16x8 af0 = *(const bf16x8*)&a_sh[(mw + l16) * 64 + so];
      bf16x8 af1 = *(const bf16x8*)&a_sh[(mw + 16 + l16) * 64 + so];
#pragma unroll
      for (int nt = 0; nt < 2; ++nt) {
        bf16x8 bfr = *(const bf16x8*)&b_sh[(nw + nt * 16 + l16) * 64 + so];
        acc[0][nt] = __builtin_amdgcn_mfma_f32_16x16x32_bf16(af0, bfr, acc[0][nt], 0, 0, 0);
        acc[1][nt] = __builtin_amdgcn_mfma_f32_16x16x32_bf16(af1, bfr, acc[1][nt], 0, 0, 0);
      }
    }
  }

#pragma unroll
  for (int nt = 0; nt < 2; ++nt) {
    const int   n  = n0 + nw + nt * 16 + l16;
    const float bv = bias[n];
#pragma unroll
    for (int mt = 0; mt < 2; ++mt)
#pragma unroll
      for (int r = 0; r < 4; ++r) {
        const int m = m0 + mw + mt * 16 + quad * 4 + r;
        out[(size_t)m * DD + n] = acc[mt][nt][r] + bv;
      }
  }
}

// ---------------------------------------------------------------- launcher
extern "C" void kernel_launch(void* const* d_in, const int* in_sizes, int n_in,
                              void* d_out, int out_size, void* d_ws, size_t ws_size,
                              hipStream_t stream) {
  (void)in_sizes; (void)n_in; (void)out_size; (void)ws_size;
  const float* x  = (const float*)d_in[0];
  const float* Wq = (const float*)d_in[1];
  const float* bq = (const float*)d_in[2];
  const float* Wk = (const float*)d_in[3];
  const float* bk = (const float*)d_in[4];
  const float* Wv = (const float*)d_in[5];
  const float* bv = (const float*)d_in[6];
  const float* Wh = (const float*)d_in[7];
  const float* bh = (const float*)d_in[8];

  short* ws  = (short*)d_ws;
  short* xb  = ws;                              // x bf16 [8192,512]; reused as Op0
  short* wqt = xb  + (size_t)MM * DD;           // Wq^T bf16 [512,512]
  short* wkt = wqt + (size_t)DD * DD;           // (wqt..wvt contiguous = QKV Bt)
  short* wvt = wkt + (size_t)DD * DD;
  short* wht = wvt + (size_t)DD * DD;
  short* qws = wht + (size_t)DD * DD;           // q bf16 [B,H,S,64] (pre-scaled)
  short* kws = qws + (size_t)MM * DD;           // k bf16 [B,H,S,64]
  short* vws = kws + (size_t)MM * DD;           // v^T bf16 [B,H,64,S]
  short* aws = vws + (size_t)MM * DD;           // attn out bf16 [B,S,512]
  short* op1 = aws + (size_t)MM * DD;           // partial O half1 [B,H,S,64]
  float* lpw = (float*)(op1 + (size_t)MM * DD); // partial l [2][B*H*S]

  hipLaunchKernelGGL(prep_kernel, dim3(2048 + 256), dim3(256), 0, stream,
                     x, xb, Wq, Wk, Wv, Wh, wqt, wkt, wvt, wht);

  // q pre-scale: (1/sqrt(64)) * log2(e) so softmax uses exp2 directly
  const float qscale = 1.4426950408889634f / 8.0f;
  hipLaunchKernelGGL(gemm_qkv_kernel, dim3(12, 128), dim3(256), 0, stream,
                     xb, wqt, bq, bk, bv, qws, kws, vws, qscale);

  // Op0 reuses xb (dead after gemm_qkv)
  hipLaunchKernelGGL(attn_kernel, dim3(1024), dim3(256), 0, stream,
                     qws, kws, vws, xb, op1, lpw);
  hipLaunchKernelGGL(attn_combine_kernel, dim3(NB * HH * SS * 8 / 256), dim3(256), 0, stream,
                     xb, op1, lpw, aws);

  hipLaunchKernelGGL(gemm_proj_kernel, dim3(8, 128), dim3(256), 0, stream,
                     aws, wht, bh, (float*)d_out);
}